// Round 1
// baseline (158.801 us; speedup 1.0000x reference)
//
#include <hip/hip_runtime.h>

// CTC batch cost (Keras ctc_batch_cost semantics), forward alpha recursion.
// B=512 blocks, 128 threads/block: thread s owns extended state s (S=97),
// all 128 threads cooperate on coalesced y_pred row loads (float4 = 4 rows/group).

constexpr int Bc = 512, Tc = 512, Cc = 128, Lc = 48, Sc = 2 * Lc + 1; // S=97
constexpr float FEPS = 1e-7f;
constexpr float FNEG = -1e30f;

__device__ __forceinline__ float logaddexpf_(float a, float b) {
    float m = fmaxf(a, b);
    return m + __logf(1.0f + __expf(-fabsf(a - b)));
}

__global__ __launch_bounds__(128)
void ctc_fwd_kernel(const int* __restrict__ y_true,
                    const float* __restrict__ y_pred,
                    float* __restrict__ out) {
    const int b = blockIdx.x;
    const int tid = threadIdx.x;

    __shared__ float lp[2][4][Cc];   // log-prob rows, double-buffered groups of 4 t-steps
    __shared__ float A[2][Sc + 2];   // alpha double buffer, 2 leading NEG pads
    __shared__ int ext_sh[Sc];
    __shared__ int skip_sh[Sc];

    // extended label sequence + skip mask
    if (tid < Sc) {
        int e = (tid & 1) ? y_true[b * Lc + (tid >> 1)] : (Cc - 1);
        ext_sh[tid] = e;
        int em2 = (tid >= 3) ? y_true[b * Lc + ((tid - 2) >> 1)] : -1; // only odd tid>=3 meaningful
        skip_sh[tid] = ((tid & 1) && e != em2) ? 1 : 0;
    }
    if (tid < 2) { A[0][tid] = FNEG; A[1][tid] = FNEG; }

    const float4* yp4 = reinterpret_cast<const float4*>(y_pred + (size_t)b * Tc * Cc);

    // group g covers t = 4g..4g+3; thread tid's float4 = row (tid>>5), classes (tid&31)*4..+3
    float4 vcur = yp4[tid];
    float4 vnext = vcur;
    int cur = 0;

    for (int g = 0; g < Tc / 4; ++g) {
        if (g + 1 < Tc / 4) vnext = yp4[(g + 1) * 128 + tid];  // prefetch next group
        const int lb = g & 1;
        float4 lv;
        lv.x = __logf(vcur.x + FEPS);
        lv.y = __logf(vcur.y + FEPS);
        lv.z = __logf(vcur.z + FEPS);
        lv.w = __logf(vcur.w + FEPS);
        *reinterpret_cast<float4*>(&lp[lb][tid >> 5][(tid & 31) * 4]) = lv;
        __syncthreads();  // lp[lb] ready (also covers ext_sh/A-pad init at g==0)

        #pragma unroll
        for (int j = 0; j < 4; ++j) {
            if (g == 0 && j == 0) {
                // alpha0: only states 0 (blank) and 1 (first label) live
                if (tid < Sc) {
                    float a0 = FNEG;
                    if (tid == 0) a0 = lp[0][0][Cc - 1];
                    else if (tid == 1) a0 = lp[0][0][ext_sh[1]];
                    A[0][2 + tid] = a0;
                }
                cur = 0;
            } else {
                const int nxt = cur ^ 1;
                if (tid < Sc) {
                    float a1 = A[cur][2 + tid];
                    float a2 = A[cur][1 + tid];
                    float a3 = skip_sh[tid] ? A[cur][tid] : FNEG;
                    float r = logaddexpf_(logaddexpf_(a1, a2), a3);
                    A[nxt][2 + tid] = r + lp[lb][j][ext_sh[tid]];
                }
                cur = nxt;
            }
            __syncthreads();  // one barrier per time step (double-buffered alpha)
        }
        vcur = vnext;
    }

    if (tid == 0) {
        float ll = logaddexpf_(A[cur][2 + Sc - 1], A[cur][2 + Sc - 2]);
        out[b] = -ll;
    }
}

extern "C" void kernel_launch(void* const* d_in, const int* in_sizes, int n_in,
                              void* d_out, int out_size, void* d_ws, size_t ws_size,
                              hipStream_t stream) {
    const int* y_true = (const int*)d_in[0];
    const float* y_pred = (const float*)d_in[1];
    float* out = (float*)d_out;
    hipLaunchKernelGGL(ctc_fwd_kernel, dim3(Bc), dim3(128), 0, stream,
                       y_true, y_pred, out);
}

// Round 3
// 50.556 us; speedup vs baseline: 3.1411x; 3.1411x over previous
//
#include <hip/hip_runtime.h>

// CTC batch cost, wave-per-batch-item, alpha in registers.
// Lane l holds extended states {2l, 2l+1}; S=97 -> lanes 0..48 live.
// One ds_bpermute per time step (neighbor hi), no barriers, no LDS tiles.
// All alphas kept in log2 domain; final result scaled by ln2.

constexpr int Bc = 512, Tc = 512, Cc = 128, Lc = 48;
constexpr float FEPS = 1e-7f;
constexpr float FNEG = -1e30f;
constexpr float LN2F = 0.69314718055994530942f;

__device__ __forceinline__ float lae2(float a, float b) {
    // log2-domain logaddexp: max + log2(1 + 2^-|a-b|)
    float m = fmaxf(a, b);
    float d = fabsf(a - b);
    return m + __log2f(1.0f + __builtin_amdgcn_exp2f(-d));
}

__global__ __launch_bounds__(64)
void ctc_wave_kernel(const int* __restrict__ y_true,
                     const float* __restrict__ y_pred,
                     float* __restrict__ out) {
    const int b = blockIdx.x;
    const int lane = threadIdx.x;

    const float* yb = y_pred + (size_t)b * Tc * Cc;

    // this lane's class: label for odd state 2l+1; blank(127) for lanes >= 48
    const int lab = (lane < Lc) ? y_true[b * Lc + lane] : (Cc - 1);
    const int prev_addr = ((lane + 63) & 63) << 2;  // bpermute byte addr of lane-1 (wrap)
    const int labm1 = __builtin_amdgcn_ds_bpermute(prev_addr, lab);
    // skip allowed iff non-blank and differs from label[l-1]; lane0 wrap reads 127
    // which is equivalent to the reference's -1 sentinel (lab != 127 already required)
    const bool skip = (lab != (Cc - 1)) && (lab != labm1);
    const bool validhi = (lane < Lc);

    float lo = FNEG, hi = FNEG;

    auto dostep = [&](float raw) {
        float lp  = __log2f(raw + FEPS);
        float lpb = __uint_as_float(
            __builtin_amdgcn_readlane(__float_as_uint(lp), 63));  // blank prob (uniform)
        float lph = validhi ? lp : FNEG;  // dead lanes: hi pins at ~-2e30 (log-zero)
        // neighbor hi (state 2l-1); lane0 reads lane63 (dead, ~-2e30 == log-zero)
        float sh  = __int_as_float(
            __builtin_amdgcn_ds_bpermute(prev_addr, __float_as_int(hi)));
        float mid = lae2(hi, lo);              // overlaps bpermute latency
        float nlo = lae2(lo, sh) + lpb;        // even state (blank): a1,a2 only
        float a3  = skip ? sh : FNEG;
        float nhi = lae2(mid, a3) + lph;       // odd state: a1,a2,a3
        lo = nlo; hi = nhi;
    };

    // 16-deep register prefetch pipeline (statically indexed)
    float pf[16];
    #pragma unroll
    for (int j = 0; j < 16; ++j) pf[j] = yb[j * Cc + lab];

    // t = 0: init alpha from lp(t=0), refill slot 0 with t=16
    {
        float raw = pf[0];
        pf[0] = yb[16 * Cc + lab];
        float lp  = __log2f(raw + FEPS);
        float lpb = __uint_as_float(
            __builtin_amdgcn_readlane(__float_as_uint(lp), 63));
        lo = (lane == 0) ? lpb : FNEG;   // state 0 = blank
        hi = (lane == 0) ? lp : FNEG;    // state 1 = label[0]
    }
    // t = 1..15 of group 0
    #pragma unroll
    for (int j = 1; j < 16; ++j) {
        float raw = pf[j];
        pf[j] = yb[(16 + j) * Cc + lab];
        dostep(raw);
    }
    // groups 1..30: steady state, prefetch t+16
    #pragma unroll 1
    for (int g = 1; g < Tc / 16 - 1; ++g) {
        const float* ybg = yb + (size_t)(g * 16 + 16) * Cc;
        #pragma unroll
        for (int j = 0; j < 16; ++j) {
            float raw = pf[j];
            pf[j] = ybg[j * Cc + lab];
            dostep(raw);
        }
    }
    // last group: t = 496..511, no more prefetch
    #pragma unroll
    for (int j = 0; j < 16; ++j) dostep(pf[j]);

    // loglik = lae(alpha[S-1], alpha[S-2]) = lae(lo@lane48, hi@lane47)
    float s96 = __int_as_float(
        __builtin_amdgcn_ds_bpermute(48 << 2, __float_as_int(lo)));
    float s95 = __int_as_float(
        __builtin_amdgcn_ds_bpermute(47 << 2, __float_as_int(hi)));
    if (lane == 0) out[b] = -(lae2(s96, s95) * LN2F);
}

extern "C" void kernel_launch(void* const* d_in, const int* in_sizes, int n_in,
                              void* d_out, int out_size, void* d_ws, size_t ws_size,
                              hipStream_t stream) {
    const int* y_true = (const int*)d_in[0];
    const float* y_pred = (const float*)d_in[1];
    float* out = (float*)d_out;
    hipLaunchKernelGGL(ctc_wave_kernel, dim3(Bc), dim3(64), 0, stream,
                       y_true, y_pred, out);
}

// Round 5
// 48.841 us; speedup vs baseline: 3.2514x; 1.0351x over previous
//
#include <hip/hip_runtime.h>

// CTC batch cost, wave-per-batch-item, alpha in registers (log2 domain).
// Lane l holds extended states {2l, 2l+1}; S=97 -> lanes 0..48 live.
// One ds_bpermute per time step, no barriers, no LDS tiles.
// Round-5 change vs round-3: register prefetch 16 -> 64 deep (MLP fix).

constexpr int Bc = 512, Tc = 512, Cc = 128, Lc = 48;
constexpr float FEPS = 1e-7f;
constexpr float FNEG = -1e30f;
constexpr float LN2F = 0.69314718055994530942f;

__device__ __forceinline__ float lae2(float a, float b) {
    // log2-domain logaddexp: max + log2(1 + 2^-|a-b|)
    float m = fmaxf(a, b);
    float d = fabsf(a - b);
    return m + __log2f(1.0f + __builtin_amdgcn_exp2f(-d));
}

__global__ __launch_bounds__(64)
void ctc_wave_kernel(const int* __restrict__ y_true,
                     const float* __restrict__ y_pred,
                     float* __restrict__ out) {
    const int b = blockIdx.x;
    const int lane = threadIdx.x;

    const float* yb = y_pred + (size_t)b * Tc * Cc;

    // this lane's class: label for odd state 2l+1; blank(127) for lanes >= 48
    const int lab = (lane < Lc) ? y_true[b * Lc + lane] : (Cc - 1);
    const int prev_addr = ((lane + 63) & 63) << 2;  // bpermute byte addr of lane-1 (wrap)
    const int labm1 = __builtin_amdgcn_ds_bpermute(prev_addr, lab);
    // skip allowed iff non-blank and differs from label[l-1]
    const bool skip = (lab != (Cc - 1)) && (lab != labm1);
    const bool validhi = (lane < Lc);

    float lo = FNEG, hi = FNEG;

    auto dostep = [&](float raw) {
        float lp  = __log2f(raw + FEPS);
        float lpb = __uint_as_float((unsigned)
            __builtin_amdgcn_readlane(__float_as_uint(lp), 63));  // blank prob (uniform)
        float lph = validhi ? lp : FNEG;  // dead lanes: hi pins at ~-2e30 (log-zero)
        // neighbor hi (state 2l-1); lane0 reads lane63 (dead, ~-2e30 == log-zero)
        float sh  = __int_as_float(
            __builtin_amdgcn_ds_bpermute(prev_addr, __float_as_int(hi)));
        float mid = lae2(hi, lo);              // overlaps bpermute latency
        float nlo = lae2(lo, sh) + lpb;        // even state (blank): a1,a2 only
        float a3  = skip ? sh : FNEG;
        float nhi = lae2(mid, a3) + lph;       // odd state: a1,a2,a3
        lo = nlo; hi = nhi;
    };

    // 64-deep register prefetch pipeline (statically indexed)
    float pf[64];
    #pragma unroll
    for (int j = 0; j < 64; ++j) pf[j] = yb[j * Cc + lab];

    // t = 0: init alpha from lp(t=0), refill slot 0 with t=64
    {
        float raw = pf[0];
        pf[0] = yb[64 * Cc + lab];
        float lp  = __log2f(raw + FEPS);
        float lpb = __uint_as_float((unsigned)
            __builtin_amdgcn_readlane(__float_as_uint(lp), 63));
        lo = (lane == 0) ? lpb : FNEG;   // state 0 = blank
        hi = (lane == 0) ? lp : FNEG;    // state 1 = label[0]
    }
    // t = 1..63 of group 0, refill t+64
    #pragma unroll
    for (int j = 1; j < 64; ++j) {
        float raw = pf[j];
        pf[j] = yb[(64 + j) * Cc + lab];
        dostep(raw);
    }
    // groups 1..6: steady state, prefetch t+64
    #pragma unroll 1
    for (int g = 1; g < Tc / 64 - 1; ++g) {
        const float* ybg = yb + (size_t)(g * 64 + 64) * Cc;
        #pragma unroll
        for (int j = 0; j < 64; ++j) {
            float raw = pf[j];
            pf[j] = ybg[j * Cc + lab];
            dostep(raw);
        }
    }
    // last group: t = 448..511, no more prefetch
    #pragma unroll
    for (int j = 0; j < 64; ++j) dostep(pf[j]);

    // loglik = lae(alpha[S-1], alpha[S-2]) = lae(lo@lane48, hi@lane47)
    float s96 = __int_as_float(
        __builtin_amdgcn_ds_bpermute(48 << 2, __float_as_int(lo)));
    float s95 = __int_as_float(
        __builtin_amdgcn_ds_bpermute(47 << 2, __float_as_int(hi)));
    if (lane == 0) out[b] = -(lae2(s96, s95) * LN2F);
}

extern "C" void kernel_launch(void* const* d_in, const int* in_sizes, int n_in,
                              void* d_out, int out_size, void* d_ws, size_t ws_size,
                              hipStream_t stream) {
    const int* y_true = (const int*)d_in[0];
    const float* y_pred = (const float*)d_in[1];
    float* out = (float*)d_out;
    hipLaunchKernelGGL(ctc_wave_kernel, dim3(Bc), dim3(64), 0, stream,
                       y_true, y_pred, out);
}

// Round 6
// 41.163 us; speedup vs baseline: 3.8578x; 1.1865x over previous
//
#include <hip/hip_runtime.h>

// CTC batch cost, forward-backward split: 2 waves per batch item.
// Wave 0: forward alpha t=0..255. Wave 1: backward beta t=511..256.
// loglik = lae_s(alpha_255[s] + beta_255[s]), combined via LDS once.
// Lane l holds extended states {2l, 2l+1}; S=97 -> lanes 0..48 live.
// Cross-lane neighbor via DPP wave_shr:1 / wave_shl:1 (update_dpp, old=FNEG
// handles the boundary lane exactly). Log2 domain throughout; lae3 flattened.

constexpr int Bc = 512, Tc = 512, Cc = 128, Lc = 48;
constexpr float FEPS = 1e-7f;
constexpr float FNEG = -1e30f;
constexpr float LN2F = 0.69314718055994530942f;

#define DPP_WAVE_SHR1 0x138
#define DPP_WAVE_SHL1 0x130

__device__ __forceinline__ float dpp_shr1(float x) {
    // lane l <- lane l-1; lane 0 <- FNEG (old operand, bound_ctrl=false)
    int r = __builtin_amdgcn_update_dpp(__float_as_int(FNEG), __float_as_int(x),
                                        DPP_WAVE_SHR1, 0xF, 0xF, false);
    return __int_as_float(r);
}
__device__ __forceinline__ float dpp_shl1(float x) {
    // lane l <- lane l+1; lane 63 <- FNEG
    int r = __builtin_amdgcn_update_dpp(__float_as_int(FNEG), __float_as_int(x),
                                        DPP_WAVE_SHL1, 0xF, 0xF, false);
    return __int_as_float(r);
}

__device__ __forceinline__ float lae2(float a, float b) {
    float m = fmaxf(a, b);
    float d = fabsf(a - b);
    return m + __log2f(1.0f + __builtin_amdgcn_exp2f(-d));
}
__device__ __forceinline__ float lae3(float a, float b, float c) {
    float m = fmaxf(fmaxf(a, b), c);  // v_max3_f32
    float s = __builtin_amdgcn_exp2f(a - m) + __builtin_amdgcn_exp2f(b - m)
            + __builtin_amdgcn_exp2f(c - m);
    return m + __log2f(s);
}

__global__ __launch_bounds__(128)
void ctc_fb_kernel(const int* __restrict__ y_true,
                   const float* __restrict__ y_pred,
                   float* __restrict__ out) {
    const int b = blockIdx.x;
    const int lane = threadIdx.x & 63;
    const int wave = threadIdx.x >> 6;

    const float* yb = y_pred + (size_t)b * Tc * Cc;

    // lane's class: label l for odd state 2l+1; blank(127) otherwise/dead
    const int lab = (lane < Lc) ? y_true[b * Lc + lane] : (Cc - 1);
    const int labm1 = __builtin_amdgcn_ds_bpermute(((lane + 63) & 63) << 2, lab);
    const int labp1 = __builtin_amdgcn_ds_bpermute(((lane + 1) & 63) << 2, lab);
    // forward: skip into state 2l+1 from 2l-1 (lane0: labm1=127(blank) => true iff lab real)
    const bool skip  = (lab != (Cc - 1)) && (lab != labm1);
    // backward: skip out of state 2l+1 into 2l+3 (lane l+1's hi-state)
    const bool skipN = (labp1 != (Cc - 1)) && (labp1 != lab);
    const bool validhi = (lane < Lc);
    const bool lane0 = (lane == 0);

    __shared__ float sblo[64], sbhi[64];

    float lo = FNEG, hi = FNEG;  // wave0 result (alpha); wave1 reuses as beta

    if (wave == 0) {
        // ---------------- forward: alpha_255, consume lp_0..lp_255 ----------
        auto dostep = [&](float raw) {
            float lp  = __log2f(raw + FEPS);
            float lpb = __uint_as_float((unsigned)
                __builtin_amdgcn_readlane(__float_as_uint(lp), 63));
            float lph = validhi ? lp : FNEG;
            float sh  = dpp_shr1(hi);            // alpha[2l-1]
            float nlo = lae2(lo, sh) + lpb;      // even state (blank)
            float a3  = skip ? sh : FNEG;
            float nhi = lae3(hi, lo, a3) + lph;  // odd state (label)
            lo = nlo; hi = nhi;
        };
        float pf[32];
        #pragma unroll
        for (int j = 0; j < 32; ++j) pf[j] = yb[j * Cc + lab];
        {   // group 0 with t=0 init
            float raw = pf[0];
            pf[0] = yb[32 * Cc + lab];
            float lp  = __log2f(raw + FEPS);
            float lpb = __uint_as_float((unsigned)
                __builtin_amdgcn_readlane(__float_as_uint(lp), 63));
            lo = lane0 ? lpb : FNEG;   // state 0 = blank
            hi = lane0 ? lp : FNEG;    // state 1 = label[0]
            #pragma unroll
            for (int j = 1; j < 32; ++j) {
                float r = pf[j];
                pf[j] = yb[(32 + j) * Cc + lab];
                dostep(r);
            }
        }
        #pragma unroll 1
        for (int g = 1; g < 7; ++g) {   // groups 1..6, refill t+32
            const float* ybg = yb + (size_t)(g * 32 + 32) * Cc;
            #pragma unroll
            for (int j = 0; j < 32; ++j) {
                float r = pf[j];
                pf[j] = ybg[j * Cc + lab];
                dostep(r);
            }
        }
        #pragma unroll
        for (int j = 0; j < 32; ++j) dostep(pf[j]);  // group 7: t=224..255
    } else {
        // ---------------- backward: beta_255, consume lp_511..lp_256 --------
        // beta_t[2l]   = lae2(q[2l], q[2l+1])            (s+2 even: never skip)
        // beta_t[2l+1] = lae3(q[2l+1], q[2l+2], skipN ? q[2l+3] : NEG)
        // with q[s] = beta_{t+1}[s] + lp_{t+1}[s]
        auto dostep = [&](float raw) {
            float lp  = __log2f(raw + FEPS);
            float lpb = __uint_as_float((unsigned)
                __builtin_amdgcn_readlane(__float_as_uint(lp), 63));
            float lpo = validhi ? lp : FNEG;
            float qlo = lo + lpb;                // q[2l]
            float qhi = hi + lpo;                // q[2l+1]
            float qlo_n = dpp_shl1(qlo);         // q[2l+2]
            float qhi_n = dpp_shl1(qhi);         // q[2l+3]
            float nlo = lae2(qlo, qhi);
            float a3  = skipN ? qhi_n : FNEG;
            float nhi = lae3(qhi, qlo_n, a3);
            lo = nlo; hi = nhi;
        };
        // init beta_511: states 96 (lane48 lo) and 95 (lane47 hi) = log(1) = 0
        lo = (lane == 48) ? 0.0f : FNEG;
        hi = (lane == 47) ? 0.0f : FNEG;
        float pf[32];
        #pragma unroll
        for (int j = 0; j < 32; ++j) pf[j] = yb[(size_t)(511 - j) * Cc + lab];
        #pragma unroll 1
        for (int g = 0; g < 7; ++g) {   // groups 0..6, refill
            #pragma unroll
            for (int j = 0; j < 32; ++j) {
                float r = pf[j];
                pf[j] = yb[(size_t)(511 - (g * 32 + 32 + j)) * Cc + lab];
                dostep(r);
            }
        }
        #pragma unroll
        for (int j = 0; j < 32; ++j) dostep(pf[j]);  // consume lp_287..lp_256
        sblo[lane] = lo;
        sbhi[lane] = hi;
    }

    __syncthreads();

    if (wave == 0) {
        // loglik = lae over states of alpha_255[s] + beta_255[s]
        float v = lae2(lo + sblo[lane], hi + sbhi[lane]);
        #pragma unroll
        for (int mk = 1; mk < 64; mk <<= 1)
            v = lae2(v, __shfl_xor(v, mk, 64));
        if (lane0) out[b] = -(v * LN2F);
    }
}

extern "C" void kernel_launch(void* const* d_in, const int* in_sizes, int n_in,
                              void* d_out, int out_size, void* d_ws, size_t ws_size,
                              hipStream_t stream) {
    const int* y_true = (const int*)d_in[0];
    const float* y_pred = (const float*)d_in[1];
    float* out = (float*)d_out;
    hipLaunchKernelGGL(ctc_fb_kernel, dim3(Bc), dim3(128), 0, stream,
                       y_true, y_pred, out);
}

// Round 9
// 31.878 us; speedup vs baseline: 4.9815x; 1.2913x over previous
//
#include <hip/hip_runtime.h>

// CTC batch cost, forward-backward split, PROBABILITY domain with per-lane
// power-of-2 scaling (exact). No transcendentals in the recurrence chain.
// Wave 0: forward alpha_255 (t=0..255). Wave 1: backward beta_255 (t=511..256).
// loglik = log(sum_s alpha_255[s]*beta_255[s]); logs only in the final combine.
// Lane l holds extended states {2l, 2l+1}; S=97 -> lanes 0..48 live.
// FIX vs round 8: value-dead lanes ADOPT the neighbor's scale unconditionally
// (m = own_dead ? c_nb : max(c, c_nb)). Round 8's max() froze a stale c on
// value-dead lanes (renorm can't decay a zero-valued lane), so by first value
// contact the scale gap was ~7*l log2 and the incoming value flushed to zero,
// killing the propagation wavefront around lane 22.

constexpr int Bc = 512, Tc = 512, Cc = 128, Lc = 48;
constexpr float FEPS = 1e-7f;
constexpr float FNEG = -1e30f;
constexpr float LN2F = 0.69314718055994530942f;
constexpr int CDEAD = -(1 << 28);  // scale of never-touched lanes

#define DPP_WAVE_SHR1 0x138
#define DPP_WAVE_SHL1 0x130

__device__ __forceinline__ float dppf_shr1(float x) {
    // lane l <- lane l-1; lane 0 <- 0.0f (alpha[-1] = 0)
    return __int_as_float(__builtin_amdgcn_update_dpp(
        0, __float_as_int(x), DPP_WAVE_SHR1, 0xF, 0xF, false));
}
__device__ __forceinline__ float dppf_shl1(float x) {
    // lane l <- lane l+1; lane 63 <- 0.0f (beta beyond last state = 0)
    return __int_as_float(__builtin_amdgcn_update_dpp(
        0, __float_as_int(x), DPP_WAVE_SHL1, 0xF, 0xF, false));
}
__device__ __forceinline__ int dppi_shr1_self(int c) {
    // lane l <- lane l-1; lane 0 <- own c
    return __builtin_amdgcn_update_dpp(c, c, DPP_WAVE_SHR1, 0xF, 0xF, false);
}
__device__ __forceinline__ int dppi_shl1_self(int c) {
    return __builtin_amdgcn_update_dpp(c, c, DPP_WAVE_SHL1, 0xF, 0xF, false);
}

__device__ __forceinline__ float lae2(float a, float b) {  // final reduce only
    float m = fmaxf(a, b);
    float d = fabsf(a - b);
    return m + __log2f(1.0f + __builtin_amdgcn_exp2f(-d));
}
__device__ __forceinline__ float blankp(float praw) {
    return __uint_as_float((unsigned)
        __builtin_amdgcn_readlane(__float_as_uint(praw), 63)) + FEPS;
}

__global__ __launch_bounds__(128)
void ctc_fb_kernel(const int* __restrict__ y_true,
                   const float* __restrict__ y_pred,
                   float* __restrict__ out) {
    const int b = blockIdx.x;
    const int lane = threadIdx.x & 63;
    const int wave = threadIdx.x >> 6;

    const float* yb = y_pred + (size_t)b * Tc * Cc;

    const int lab = (lane < Lc) ? y_true[b * Lc + lane] : (Cc - 1);
    const int labm1 = __builtin_amdgcn_ds_bpermute(((lane + 63) & 63) << 2, lab);
    const int labp1 = __builtin_amdgcn_ds_bpermute(((lane + 1) & 63) << 2, lab);
    const bool skip  = (lab != (Cc - 1)) && (lab != labm1);   // into 2l+1 from 2l-1
    const bool skipN = (labp1 != (Cc - 1)) && (labp1 != lab); // out of 2l+1 into 2l+3
    const bool validhi = (lane < Lc);
    const bool lane0 = (lane == 0);

    __shared__ float sblo[64], sbhi[64];
    __shared__ int sbc[64];

    float lo = 0.0f, hi = 0.0f;
    int c = CDEAD;

    auto renorm = [&]() {
        float mx = fmaxf(lo, hi);
        int e = (int)((__float_as_uint(mx) >> 23) & 0xFF) - 127;
        e = (mx > 0.0f) ? e : 0;           // value-0 lanes: scale unchanged
        lo = ldexpf(lo, -e);
        hi = ldexpf(hi, -e);
        c += e;
    };

    if (wave == 0) {
        // -------- forward: alpha_255, consume p_0..p_255 --------
        auto dostep = [&](float praw) {
            float pb = blankp(praw);
            float ph = validhi ? (praw + FEPS) : 0.0f;  // dead lanes: hi stays 0
            float sh  = dppf_shr1(hi);       // alpha[2l-1] (value)
            int   cm1 = dppi_shr1_self(c);   // its scale
            bool  own_dead = (lo == 0.0f) && (hi == 0.0f);
            int   m  = own_dead ? cm1 : ((c > cm1) ? c : cm1);  // dead: TRACK nb scale
            float lov = ldexpf(lo, c - m);
            float hiv = ldexpf(hi, c - m);
            float shv = ldexpf(sh, cm1 - m);
            float a3  = skip ? shv : 0.0f;
            lo = (lov + shv) * pb;           // even state (blank)
            hi = (hiv + lov + a3) * ph;      // odd state (label)
            c = m;
        };
        float pf[32];
        #pragma unroll
        for (int j = 0; j < 32; ++j) pf[j] = yb[j * Cc + lab];
        {   // group 0 with t=0 init
            float praw = pf[0];
            pf[0] = yb[32 * Cc + lab];
            float pb0 = blankp(praw);
            lo = lane0 ? pb0 : 0.0f;                  // state 0 = blank
            hi = lane0 ? (praw + FEPS) : 0.0f;        // state 1 = label[0]
            c  = lane0 ? 0 : CDEAD;
            #pragma unroll
            for (int j = 1; j < 32; ++j) {
                float r = pf[j];
                pf[j] = yb[(32 + j) * Cc + lab];
                dostep(r);
                if ((j & 7) == 7) renorm();
            }
        }
        #pragma unroll 1
        for (int g = 1; g < 7; ++g) {
            const float* ybg = yb + (size_t)(g * 32 + 32) * Cc;
            #pragma unroll
            for (int j = 0; j < 32; ++j) {
                float r = pf[j];
                pf[j] = ybg[j * Cc + lab];
                dostep(r);
                if ((j & 7) == 7) renorm();
            }
        }
        #pragma unroll
        for (int j = 0; j < 32; ++j) {
            dostep(pf[j]);
            if ((j & 7) == 7) renorm();
        }
    } else {
        // -------- backward: beta_255, consume p_511..p_256 --------
        // q[s] = beta_{t+1}[s] * p_{t+1}[s]
        // beta_t[2l]   = q[2l] + q[2l+1]
        // beta_t[2l+1] = q[2l+1] + q[2l+2] + (skipN ? q[2l+3] : 0)
        auto dostep = [&](float praw) {
            float pb = blankp(praw);
            float ph = validhi ? (praw + FEPS) : 0.0f;
            float qlo = lo * pb;             // q[2l]
            float qhi = hi * ph;             // q[2l+1]
            float qlo_n = dppf_shl1(qlo);    // q[2l+2] (scale c_{l+1})
            float qhi_n = dppf_shl1(qhi);    // q[2l+3]
            int   cp1 = dppi_shl1_self(c);
            bool  own_dead = (qlo == 0.0f) && (qhi == 0.0f);
            int   m  = own_dead ? cp1 : ((c > cp1) ? c : cp1);  // dead: TRACK nb scale
            float nb = skipN ? (qlo_n + qhi_n) : qlo_n;
            lo = ldexpf(qlo + qhi, c - m);
            hi = ldexpf(qhi, c - m) + ldexpf(nb, cp1 - m);
            c = m;
        };
        // init beta_511: state 96 (lane48.lo) = 1, state 95 (lane47.hi) = 1
        lo = (lane == 48) ? 1.0f : 0.0f;
        hi = (lane == 47) ? 1.0f : 0.0f;
        c = (lane == 47 || lane == 48) ? 0 : CDEAD;
        float pf[32];
        #pragma unroll
        for (int j = 0; j < 32; ++j) pf[j] = yb[(size_t)(511 - j) * Cc + lab];
        #pragma unroll 1
        for (int g = 0; g < 7; ++g) {
            #pragma unroll
            for (int j = 0; j < 32; ++j) {
                float r = pf[j];
                pf[j] = yb[(size_t)(511 - (g * 32 + 32 + j)) * Cc + lab];
                dostep(r);
                if ((j & 7) == 7) renorm();
            }
        }
        #pragma unroll
        for (int j = 0; j < 32; ++j) {
            dostep(pf[j]);
            if ((j & 7) == 7) renorm();
        }
        sblo[lane] = lo;
        sbhi[lane] = hi;
        sbc[lane]  = c;
    }

    __syncthreads();

    if (wave == 0) {
        // loglik = log2( sum_s alpha_255[s] * beta_255[s] * 2^(ca+cb) )
        float blo = sblo[lane], bhi = sbhi[lane];
        float ctot = (float)(c + sbc[lane]);
        float plo = lo * blo;
        float phi = hi * bhi;
        float yl = (plo > 0.0f) ? (__log2f(plo) + ctot) : FNEG;
        float yh = (phi > 0.0f) ? (__log2f(phi) + ctot) : FNEG;
        float v = lae2(yl, yh);
        #pragma unroll
        for (int mk = 1; mk < 64; mk <<= 1)
            v = lae2(v, __shfl_xor(v, mk, 64));
        if (lane0) out[b] = -(v * LN2F);
    }
}

extern "C" void kernel_launch(void* const* d_in, const int* in_sizes, int n_in,
                              void* d_out, int out_size, void* d_ws, size_t ws_size,
                              hipStream_t stream) {
    const int* y_true = (const int*)d_in[0];
    const float* y_pred = (const float*)d_in[1];
    float* out = (float*)d_out;
    hipLaunchKernelGGL(ctc_fb_kernel, dim3(Bc), dim3(128), 0, stream,
                       y_true, y_pred, out);
}

// Round 11
// 30.196 us; speedup vs baseline: 5.2590x; 1.0557x over previous
//
#include <hip/hip_runtime.h>

// CTC batch cost, forward-backward split, probability domain in FLOAT64 with
// wave-uniform power-of-2 renorm every 32 steps (exact; integer c).
// f64's +-1022 exponent range >> the ~300 log2 cross-state spread, so the
// wave-global window failure of the f32 variant (round 10) cannot occur.
// Wave 0: forward alpha_255 (t=0..255). Wave 1: backward beta_255 (t=511..256).
// loglik = log2(sum_s alpha_255[s]*beta_255[s]*2^(ca+cb)).
// Lane l holds extended states {2l, 2l+1}; S=97 -> lanes 0..48 live.

constexpr int Bc = 512, Tc = 512, Cc = 128, Lc = 48;
constexpr double DEPS = 1e-7;
constexpr float FNEG = -1e30f;
constexpr float LN2F = 0.69314718055994530942f;

#define DPP_WAVE_SHR1 0x138
#define DPP_WAVE_SHL1 0x130

__device__ __forceinline__ double dpp64_shr1(double x) {
    // lane l <- lane l-1; lane 0 <- 0.0
    long long u = __double_as_longlong(x);
    int a = __builtin_amdgcn_update_dpp(0, (int)u,         DPP_WAVE_SHR1, 0xF, 0xF, false);
    int b = __builtin_amdgcn_update_dpp(0, (int)(u >> 32), DPP_WAVE_SHR1, 0xF, 0xF, false);
    return __longlong_as_double(((long long)b << 32) | (unsigned int)a);
}
__device__ __forceinline__ double dpp64_shl1(double x) {
    // lane l <- lane l+1; lane 63 <- 0.0
    long long u = __double_as_longlong(x);
    int a = __builtin_amdgcn_update_dpp(0, (int)u,         DPP_WAVE_SHL1, 0xF, 0xF, false);
    int b = __builtin_amdgcn_update_dpp(0, (int)(u >> 32), DPP_WAVE_SHL1, 0xF, 0xF, false);
    return __longlong_as_double(((long long)b << 32) | (unsigned int)a);
}

__device__ __forceinline__ float lae2(float a, float b) {  // final reduce only
    float m = fmaxf(a, b);
    float d = fabsf(a - b);
    return m + __log2f(1.0f + __builtin_amdgcn_exp2f(-d));
}
__device__ __forceinline__ float blankpf(float praw) {
    return __uint_as_float((unsigned)
        __builtin_amdgcn_readlane(__float_as_uint(praw), 63));
}
__device__ __forceinline__ float log2d(double x) {
    // log2 of a positive normal f64; zero/denormal -> log-zero
    if (!(x > 0.0)) return FNEG;
    long long u = __double_as_longlong(x);
    int e = (int)((u >> 52) & 0x7FF);
    if (e == 0) return FNEG;  // denormal: far below any relevant state
    double m = __longlong_as_double((u & 0x000FFFFFFFFFFFFFLL) | 0x3FF0000000000000LL);
    return __log2f((float)m) + (float)(e - 1023);
}

__global__ __launch_bounds__(128)
void ctc_fb_kernel(const int* __restrict__ y_true,
                   const float* __restrict__ y_pred,
                   float* __restrict__ out) {
    const int b = blockIdx.x;
    const int lane = threadIdx.x & 63;
    const int wave = threadIdx.x >> 6;

    const float* yb = y_pred + (size_t)b * Tc * Cc;

    const int lab = (lane < Lc) ? y_true[b * Lc + lane] : (Cc - 1);
    const int labm1 = __builtin_amdgcn_ds_bpermute(((lane + 63) & 63) << 2, lab);
    const int labp1 = __builtin_amdgcn_ds_bpermute(((lane + 1) & 63) << 2, lab);
    const bool skip  = (lab != (Cc - 1)) && (lab != labm1);   // into 2l+1 from 2l-1
    const bool skipN = (labp1 != (Cc - 1)) && (labp1 != lab); // out of 2l+1 into 2l+3
    const bool validhi = (lane < Lc);
    const bool lane0 = (lane == 0);

    __shared__ double sblo[64], sbhi[64];
    __shared__ int sbc[64];

    double lo = 0.0, hi = 0.0;
    int c = 0;   // wave-uniform log2 scale (exact integer)

    auto renorm = [&]() {   // once per 32 steps; wave max via shuffles
        double mx = fmax(lo, hi);
        #pragma unroll
        for (int mk = 1; mk < 64; mk <<= 1)
            mx = fmax(mx, __shfl_xor(mx, mk, 64));
        int e = (int)((__double_as_longlong(mx) >> 52) & 0x7FF) - 1023;
        double sc = __longlong_as_double((long long)(1023 - e) << 52);  // exact 2^-e
        lo *= sc; hi *= sc;
        c += e;
    };

    if (wave == 0) {
        // -------- forward: alpha_255, consume p_0..p_255 --------
        auto dostep = [&](float praw) {
            double pb = (double)blankpf(praw) + DEPS;
            double ph = validhi ? ((double)praw + DEPS) : 0.0;
            double sh = dpp64_shr1(hi);        // alpha[2l-1]
            double a3 = skip ? sh : 0.0;
            double nlo = (lo + sh) * pb;       // even state (blank)
            double nhi = (hi + lo + a3) * ph;  // odd state (label)
            lo = nlo; hi = nhi;
        };
        float pf[32];
        #pragma unroll
        for (int j = 0; j < 32; ++j) pf[j] = yb[j * Cc + lab];
        {   // group 0 with t=0 init
            float praw = pf[0];
            pf[0] = yb[32 * Cc + lab];
            lo = lane0 ? ((double)blankpf(praw) + DEPS) : 0.0;  // state 0 = blank
            hi = lane0 ? ((double)praw + DEPS) : 0.0;           // state 1 = label[0]
            #pragma unroll
            for (int j = 1; j < 32; ++j) {
                float r = pf[j];
                pf[j] = yb[(32 + j) * Cc + lab];
                dostep(r);
            }
            renorm();
        }
        #pragma unroll 1
        for (int g = 1; g < 7; ++g) {
            const float* ybg = yb + (size_t)(g * 32 + 32) * Cc;
            #pragma unroll
            for (int j = 0; j < 32; ++j) {
                float r = pf[j];
                pf[j] = ybg[j * Cc + lab];
                dostep(r);
            }
            renorm();
        }
        #pragma unroll
        for (int j = 0; j < 32; ++j) dostep(pf[j]);
        renorm();
    } else {
        // -------- backward: beta_255, consume p_511..p_256 --------
        // q[s] = beta_{t+1}[s] * p_{t+1}[s]
        // beta_t[2l]   = q[2l] + q[2l+1]
        // beta_t[2l+1] = q[2l+1] + q[2l+2] + (skipN ? q[2l+3] : 0)
        auto dostep = [&](float praw) {
            double pb = (double)blankpf(praw) + DEPS;
            double ph = validhi ? ((double)praw + DEPS) : 0.0;
            double qlo = lo * pb;              // q[2l]
            double qhi = hi * ph;              // q[2l+1]
            double qlo_n = dpp64_shl1(qlo);    // q[2l+2]
            double qhi_n = dpp64_shl1(qhi);    // q[2l+3]
            double nb = skipN ? (qlo_n + qhi_n) : qlo_n;
            lo = qlo + qhi;
            hi = qhi + nb;
        };
        // init beta_511: state 96 (lane48.lo) = 1, state 95 (lane47.hi) = 1
        lo = (lane == 48) ? 1.0 : 0.0;
        hi = (lane == 47) ? 1.0 : 0.0;
        float pf[32];
        #pragma unroll
        for (int j = 0; j < 32; ++j) pf[j] = yb[(size_t)(511 - j) * Cc + lab];
        #pragma unroll 1
        for (int g = 0; g < 7; ++g) {
            #pragma unroll
            for (int j = 0; j < 32; ++j) {
                float r = pf[j];
                pf[j] = yb[(size_t)(511 - (g * 32 + 32 + j)) * Cc + lab];
                dostep(r);
            }
            renorm();
        }
        #pragma unroll
        for (int j = 0; j < 32; ++j) dostep(pf[j]);
        renorm();
        sblo[lane] = lo;
        sbhi[lane] = hi;
        sbc[lane]  = c;
    }

    __syncthreads();

    if (wave == 0) {
        // loglik = log2( sum_s alpha_255[s]*beta_255[s] ) + ca + cb
        double plo = lo * sblo[lane];
        double phi = hi * sbhi[lane];
        float ctot = (float)(c + sbc[lane]);
        float yl = log2d(plo) + ctot;
        float yh = log2d(phi) + ctot;
        float v = lae2(yl, yh);
        #pragma unroll
        for (int mk = 1; mk < 64; mk <<= 1)
            v = lae2(v, __shfl_xor(v, mk, 64));
        if (lane0) out[b] = -(v * LN2F);
    }
}

extern "C" void kernel_launch(void* const* d_in, const int* in_sizes, int n_in,
                              void* d_out, int out_size, void* d_ws, size_t ws_size,
                              hipStream_t stream) {
    const int* y_true = (const int*)d_in[0];
    const float* y_pred = (const float*)d_in[1];
    float* out = (float*)d_out;
    hipLaunchKernelGGL(ctc_fb_kernel, dim3(Bc), dim3(128), 0, stream,
                       y_true, y_pred, out);
}